// Round 10
// baseline (136.189 us; speedup 1.0000x reference)
//
#include <hip/hip_runtime.h>
#include <stdint.h>

// DenseAttention_61598420959334 — round 10:
//   k_gram: 4-tile batched regions, __syncthreads-only (race-safe).
//     - 8 global loads burst per region (64KB/block in flight; fixes the
//       vmcnt(0)-drain duty cycle that capped r5-r8 at ~2.2 TB/s)
//     - v_cvt_pk_bf16_f32 conversion (~4x fewer VALU; hi/lo self-correcting)
//     - GRAM via ds_read_b64_tr_b16, byte-identical math to r8 (HW-verified)
//   k_reduce / k_mid / k_out16 = r8 versions (all passed).

#define DD 128
#define ROWS_PER_BLK 1024
#define KSTEPS 32
#define PART_STRIDE 16512  // 16384 G-partial + 128 s-partial

// tr-read LDS layout (shorts): x[j][a], j=8g+4r4+e, a=16*ab+ac
//   short off = 648*ab + 320*r4 + 64*g + 16*e + ac
#define AB_STRIDE 648
#define R_STRIDE  320
#define PLANE_SH  5184            // shorts per plane
#define PLANE_B   10368           // bytes per plane
#define TILE_B    20736           // bytes per tile (2 planes)

typedef float f32x4 __attribute__((ext_vector_type(4)));
typedef short s16x8 __attribute__((ext_vector_type(8)));
typedef float fvec4 __attribute__((ext_vector_type(4)));

__device__ __forceinline__ unsigned short f2bf(float f) {
    union { float f; uint32_t u; } v; v.f = f;
    uint32_t u = v.u;
    u += 0x7FFFu + ((u >> 16) & 1u);
    return (unsigned short)(u >> 16);
}
__device__ __forceinline__ float u2f(uint32_t u) {
    union { uint32_t u; float f; } v; v.u = u; return v.f;
}
__device__ __forceinline__ s16x8 mk8(uint64_t lo, uint64_t hi) {
    union { uint64_t u[2]; s16x8 v; } x; x.u[0] = lo; x.u[1] = hi; return x.v;
}

// ---------------------------------------------------------------- pass 1: Gram
__global__ __launch_bounds__(512) void k_gram(const float* __restrict__ x,
                                              float* __restrict__ ws,
                                              unsigned short* __restrict__ x16) {
    __shared__ __align__(16) short lds[4][2][PLANE_SH];  // 4 tiles, 83 KB

    const int tid = threadIdx.x;
    const int l = tid & 63, w = tid >> 6;
    const int hi = l >> 4, c = l & 15;
    const int wr = w >> 1, wc = w & 1;
    const long rowbase = (long)blockIdx.x * ROWS_PER_BLK;
    const fvec4* xg = (const fvec4*)x;

    s16x8 ones;
#pragma unroll
    for (int i = 0; i < 8; ++i) ones[i] = (short)0x3F80;

    f32x4 acc[2][4] = {};
    f32x4 accs = {};

    // per-lane tr-read base addresses (byte offsets into LDS)
    const unsigned lbase = (unsigned)(uintptr_t)&lds[0][0][0];
    const unsigned vA = lbase + 2592u * (unsigned)wr + 8u * (unsigned)l;
    const unsigned vB = lbase + 5184u * (unsigned)wc + 8u * (unsigned)l;

#define LOADS(kt, r0, r1) do {                                  \
        long _b = (rowbase + (long)(kt) * 32) * 32;             \
        r0 = xg[_b + tid]; r1 = xg[_b + 512 + tid];             \
    } while (0)

    // hi/lo bf16 split via v_cvt_pk_bf16_f32; write tr-subtiled; dump hi plane
#define CVT(T, KT, r0, r1) do {                                                 \
        _Pragma("unroll")                                                       \
        for (int _q = 0; _q < 2; ++_q) {                                        \
            fvec4 _v = _q ? r1 : r0;                                            \
            int _ft = tid + _q * 512;                                           \
            int _j = _ft >> 5, _d0 = (_ft & 31) * 4;                            \
            uint32_t _h0, _h1, _q0, _q1;                                        \
            asm("v_cvt_pk_bf16_f32 %0, %1, %2" : "=v"(_h0) : "v"(_v[0]), "v"(_v[1])); \
            asm("v_cvt_pk_bf16_f32 %0, %1, %2" : "=v"(_h1) : "v"(_v[2]), "v"(_v[3])); \
            float _l0 = _v[0] - u2f(_h0 << 16);                                 \
            float _l1 = _v[1] - u2f(_h0 & 0xffff0000u);                         \
            float _l2 = _v[2] - u2f(_h1 << 16);                                 \
            float _l3 = _v[3] - u2f(_h1 & 0xffff0000u);                         \
            asm("v_cvt_pk_bf16_f32 %0, %1, %2" : "=v"(_q0) : "v"(_l0), "v"(_l1)); \
            asm("v_cvt_pk_bf16_f32 %0, %1, %2" : "=v"(_q1) : "v"(_l2), "v"(_l3)); \
            uint64_t _ph = (uint64_t)_h0 | ((uint64_t)_h1 << 32);               \
            uint64_t _pl = (uint64_t)_q0 | ((uint64_t)_q1 << 32);               \
            int _off = AB_STRIDE * (_d0 >> 4) + R_STRIDE * ((_j >> 2) & 1) +    \
                       64 * (_j >> 3) + 16 * (_j & 3) + (_d0 & 15);             \
            *(uint64_t*)&lds[T][0][_off] = _ph;                                 \
            *(uint64_t*)&lds[T][1][_off] = _pl;                                 \
            if (x16)                                                            \
                *(uint64_t*)&x16[(rowbase + (long)(KT) * 32 + _j) * 128 + _d0] = _ph; \
        }                                                                       \
    } while (0)

    // Gram update from tile T via hardware transpose reads (r8-verified math)
#define GRAM(T) do {                                                            \
        uint64_t fa[2][2][2]; /* [mi][plane][r] */                              \
        uint64_t fb[4][2][2]; /* [ni][plane][r] */                              \
        _Pragma("unroll")                                                       \
        for (int _mi = 0; _mi < 2; ++_mi)                                       \
            _Pragma("unroll")                                                   \
            for (int _hl = 0; _hl < 2; ++_hl)                                   \
                _Pragma("unroll")                                               \
                for (int _r = 0; _r < 2; ++_r) {                                \
                    unsigned _ad = vA + (unsigned)((T) * TILE_B +               \
                        _hl * PLANE_B + _mi * 1296 + _r * 640);                 \
                    asm volatile("ds_read_b64_tr_b16 %0, %1"                    \
                                 : "=v"(fa[_mi][_hl][_r]) : "v"(_ad));          \
                }                                                               \
        _Pragma("unroll")                                                       \
        for (int _ni = 0; _ni < 4; ++_ni)                                       \
            _Pragma("unroll")                                                   \
            for (int _hl = 0; _hl < 2; ++_hl)                                   \
                _Pragma("unroll")                                               \
                for (int _r = 0; _r < 2; ++_r) {                                \
                    unsigned _ad = vB + (unsigned)((T) * TILE_B +               \
                        _hl * PLANE_B + _ni * 1296 + _r * 640);                 \
                    asm volatile("ds_read_b64_tr_b16 %0, %1"                    \
                                 : "=v"(fb[_ni][_hl][_r]) : "v"(_ad));          \
                }                                                               \
        asm volatile("s_waitcnt lgkmcnt(0)" ::: "memory");                      \
        __builtin_amdgcn_sched_barrier(0);                                      \
        s16x8 Ah[2], Al[2];                                                     \
        _Pragma("unroll")                                                       \
        for (int _mi = 0; _mi < 2; ++_mi) {                                     \
            Ah[_mi] = mk8(fa[_mi][0][0], fa[_mi][0][1]);                        \
            Al[_mi] = mk8(fa[_mi][1][0], fa[_mi][1][1]);                        \
        }                                                                       \
        _Pragma("unroll")                                                       \
        for (int _ni = 0; _ni < 4; ++_ni) {                                     \
            s16x8 Bh = mk8(fb[_ni][0][0], fb[_ni][0][1]);                       \
            s16x8 Bl = mk8(fb[_ni][1][0], fb[_ni][1][1]);                       \
            _Pragma("unroll")                                                   \
            for (int _mi = 0; _mi < 2; ++_mi) {                                 \
                acc[_mi][_ni] = __builtin_amdgcn_mfma_f32_16x16x32_bf16(Ah[_mi], Bh, acc[_mi][_ni], 0, 0, 0); \
                acc[_mi][_ni] = __builtin_amdgcn_mfma_f32_16x16x32_bf16(Ah[_mi], Bl, acc[_mi][_ni], 0, 0, 0); \
                acc[_mi][_ni] = __builtin_amdgcn_mfma_f32_16x16x32_bf16(Al[_mi], Bh, acc[_mi][_ni], 0, 0, 0); \
            }                                                                   \
            if (_ni == wr) {                                                    \
                accs = __builtin_amdgcn_mfma_f32_16x16x32_bf16(ones, Bh, accs, 0, 0, 0); \
                accs = __builtin_amdgcn_mfma_f32_16x16x32_bf16(ones, Bl, accs, 0, 0, 0); \
            }                                                                   \
        }                                                                       \
    } while (0)

    fvec4 p0a, p0b, p1a, p1b, p2a, p2b, p3a, p3b;

#pragma unroll 1
    for (int rg = 0; rg < KSTEPS / 4; ++rg) {
        int kt0 = rg * 4;
        // burst-issue 8 vector loads (64 KB/block in flight)
        LOADS(kt0 + 0, p0a, p0b);
        LOADS(kt0 + 1, p1a, p1b);
        LOADS(kt0 + 2, p2a, p2b);
        LOADS(kt0 + 3, p3a, p3b);
        // convert as data lands (compiler inserts counted vmcnt per tile)
        CVT(0, kt0 + 0, p0a, p0b);
        CVT(1, kt0 + 1, p1a, p1b);
        CVT(2, kt0 + 2, p2a, p2b);
        CVT(3, kt0 + 3, p3a, p3b);
        __syncthreads();
        GRAM(0); GRAM(1); GRAM(2); GRAM(3);
        __syncthreads();
    }

    long pbase = (long)blockIdx.x * PART_STRIDE;
#pragma unroll
    for (int mi = 0; mi < 2; ++mi)
#pragma unroll
        for (int ni = 0; ni < 4; ++ni)
#pragma unroll
            for (int e = 0; e < 4; ++e) {
                int a = (wr * 2 + mi) * 16 + hi * 4 + e;
                int b = (wc * 4 + ni) * 16 + c;
                ws[pbase + a * 128 + b] = acc[mi][ni][e];
            }
    if (hi == 0) {
        int nbs = wc * 4 + wr;
        ws[pbase + 16384 + nbs * 16 + c] = accs[0];
    }
#undef LOADS
#undef CVT
#undef GRAM
}

// ------------------------------------------------------- reduce partials -> G, s
__global__ __launch_bounds__(256) void k_reduce(const float* __restrict__ parts,
                                                float* __restrict__ g_out,
                                                float* __restrict__ s_out, int nb1) {
    __shared__ float red[256];
    int b = blockIdx.x, t = threadIdx.x;
    if (b < 512) {
        int d1 = b >> 2, q = b & 3;
        int c32 = t & 31, pg = t >> 5;
        int per = nb1 >> 3;
        int e = d1 * 128 + q * 32 + c32;
        float acc = 0.f;
#pragma unroll 4
        for (int p = pg * per; p < (pg + 1) * per; ++p)
            acc += parts[(long)p * PART_STRIDE + e];
        red[t] = acc;
        __syncthreads();
        if (pg == 0) {
            float s = red[c32];
#pragma unroll
            for (int k = 1; k < 8; ++k) s += red[k * 32 + c32];
            g_out[e] = s;
        }
    } else {
        int ee = t & 127, hg = t >> 7;
        int per = nb1 >> 1;
        float acc = 0.f;
#pragma unroll 4
        for (int p = hg * per; p < (hg + 1) * per; ++p)
            acc += parts[(long)p * PART_STRIDE + 16384 + ee];
        red[t] = acc;
        __syncthreads();
        if (hg == 0) s_out[ee] = red[ee] + red[128 + ee];
    }
}

// ---- k_mid: scores row a from G (in LDS) + softmax + M row + c/wsum + casts
__global__ __launch_bounds__(256) void k_mid(const float* __restrict__ G,
                                             const float* __restrict__ s,
                                             const float* __restrict__ Wq,
                                             const float* __restrict__ bq,
                                             const float* __restrict__ Wk,
                                             const float* __restrict__ bk,
                                             const float* __restrict__ Wv,
                                             const float* __restrict__ bv,
                                             const float* __restrict__ Wo,
                                             unsigned short* __restrict__ M16,
                                             unsigned short* __restrict__ Wo16,
                                             float* __restrict__ cvec,
                                             float* __restrict__ wsum, float Bn) {
    __shared__ float gl[16384];      // G row-major
    __shared__ float wk[128 * 129];  // Wk padded (conflict-free row reads)
    __shared__ float wqr[128], sl[128], bkl[128], bvl[128];
    __shared__ float prt[2][128], prt2[2][128];
    __shared__ float tmp[128], scl[128], wrow[128], scl2[128];
    int t = threadIdx.x, a = blockIdx.x;
    int tt = t & 127, seg = t >> 7;

    {
        const fvec4* gg = (const fvec4*)G;
        fvec4* gs = (fvec4*)gl;
        for (int i = t; i < 4096; i += 256) gs[i] = gg[i];
    }
    for (int idx = t; idx < 16384; idx += 256) {
        int r = idx >> 7, cc = idx & 127;
        wk[r * 129 + cc] = Wk[idx];
    }
    if (t < 128) {
        wqr[t] = Wq[a * 128 + t];
        sl[t] = s[t]; bkl[t] = bk[t]; bvl[t] = bv[t];
    }
    __syncthreads();

    float tm = 0.f;
#pragma unroll 8
    for (int d1 = seg * 64; d1 < seg * 64 + 64; ++d1) tm += wqr[d1] * gl[d1 * 128 + tt];
    prt[seg][tt] = tm;
    __syncthreads();
    if (t < 128) tmp[t] = prt[0][t] + prt[1][t];
    __syncthreads();

    float p1 = 0.f, p2 = 0.f;
#pragma unroll 8
    for (int d = seg * 64; d < seg * 64 + 64; ++d) {
        float w2 = wk[tt * 129 + d];
        p1 += tmp[d] * w2;
        p2 += sl[d] * w2;
    }
    prt[seg][tt] = p1;
    prt2[seg][tt] = p2;
    __syncthreads();
    if (t < 128) {
        float tdot = prt[0][t] + prt[1][t];
        float kdot = prt2[0][t] + prt2[1][t];
        float qs = 0.f;
#pragma unroll 8
        for (int d = 0; d < 128; ++d) qs += wqr[d] * sl[d];
        float bqa = bq[a];
        float sc = (tdot + qs * bkl[t] + bqa * kdot + Bn * bqa * bkl[t]) *
                   0.0883883476483184406f;
        scl[t] = sc;
    }
    __syncthreads();
    if (t < 128) {
        float mx = -1e30f;
        for (int i2 = 0; i2 < 128; ++i2) mx = fmaxf(mx, scl[i2]);
        scl2[t] = expf(scl[t] - mx);
    }
    __syncthreads();
    if (t < 128) {
        float sum = 0.f;
        for (int i2 = 0; i2 < 128; ++i2) sum += scl2[i2];
        wrow[t] = scl2[t] / sum;
    }
    __syncthreads();

    float pm = 0.f;
#pragma unroll 8
    for (int cc = seg * 64; cc < seg * 64 + 64; ++cc)
        pm += wrow[cc] * Wv[cc * 128 + tt];
    prt[seg][tt] = pm;
    __syncthreads();
    if (t < 128) {
        M16[a * 128 + t] = f2bf(prt[0][t] + prt[1][t]);
        float wo = Wo[a * 128 + t];
        Wo16[a * 128 + t] = f2bf(wo);
        scl[t] = wrow[t] * bvl[t];
        scl2[t] = wo;
    }
    __syncthreads();
    if (t < 64) { scl[t] += scl[t + 64]; scl2[t] += scl2[t + 64]; }
    __syncthreads();
    if (t == 0) {
        float cv = 0.f, wsm = 0.f;
        for (int cc = 0; cc < 64; ++cc) { cv += scl[cc]; wsm += scl2[cc]; }
        cvec[a] = cv; wsum[a] = wsm;
    }
}

// ---------------- pass 2 (bf16 input): per-group double GEMM -> output rows
__global__ __launch_bounds__(256, 2) void k_out16(const unsigned short* __restrict__ x16,
                                                  const unsigned short* __restrict__ M16,
                                                  const unsigned short* __restrict__ Wo16,
                                                  const float* __restrict__ cvec,
                                                  const float* __restrict__ wsum,
                                                  const float* __restrict__ bo,
                                                  float* __restrict__ out, int ngrp) {
    __shared__ short xsk[16384];  // X_p bf16 (XOR-swizzled); reused as U^T
    __shared__ float csl[128], wsl[128], bol[128];
    int t = threadIdx.x;
    int l = t & 63, w = t >> 6, hi = l >> 4, c = l & 15;
    int p = blockIdx.x;

    // stage row-major bf16 tile, swizzling on LDS write
    const s16x8* xg = (const s16x8*)(x16 + (size_t)p * 16384);
    s16x8 stg[8];
#pragma unroll
    for (int kk = 0; kk < 8; ++kk) stg[kk] = xg[kk * 256 + t];

    s16x8 bfM[2][4];
#pragma unroll
    for (int rt = 0; rt < 2; ++rt) {
        int r = (2 * w + rt) * 16 + c;
#pragma unroll
        for (int ks = 0; ks < 4; ++ks)
            bfM[rt][ks] = *(const s16x8*)&M16[r * 128 + ks * 32 + hi * 8];
    }
    if (t < 128) { csl[t] = cvec[t]; wsl[t] = wsum[t]; bol[t] = bo[t]; }

#pragma unroll
    for (int kk = 0; kk < 8; ++kk) {
        int ft = kk * 256 + t;
        int j = ft >> 4, d08 = (ft & 15) * 8;
        *(s16x8*)&xsk[j * 128 + (d08 ^ ((j & 7) << 3))] = stg[kk];
    }
    __syncthreads();

    // GEMM1: U[j][r] = sum_d X[j,d] M[r,d]
    f32x4 acc[8][2] = {};
#pragma unroll
    for (int jt = 0; jt < 8; ++jt) {
        int j = jt * 16 + c;
        s16x8 af[4];
#pragma unroll
        for (int ks = 0; ks < 4; ++ks)
            af[ks] = *(const s16x8*)&xsk[j * 128 + ((ks * 32 + hi * 8) ^ ((j & 7) << 3))];
#pragma unroll
        for (int rt = 0; rt < 2; ++rt)
#pragma unroll
            for (int ks = 0; ks < 4; ++ks)
                acc[jt][rt] = __builtin_amdgcn_mfma_f32_16x16x32_bf16(af[ks], bfM[rt][ks], acc[jt][rt], 0, 0, 0);
    }
    __syncthreads();

    // write U^T into the same buffer
#pragma unroll
    for (int jt = 0; jt < 8; ++jt)
#pragma unroll
        for (int rt = 0; rt < 2; ++rt) {
            int r = (2 * w + rt) * 16 + c;
            int j0 = jt * 16 + hi * 4;
            uint64_t pk = 0;
#pragma unroll
            for (int e = 0; e < 4; ++e) pk |= (uint64_t)f2bf(acc[jt][rt][e]) << (16 * e);
            *(uint64_t*)&xsk[r * 128 + (j0 ^ ((r & 7) << 3))] = pk;
        }
    __syncthreads();

    s16x8 bfO[2][4];
#pragma unroll
    for (int ot = 0; ot < 2; ++ot) {
        int o = (2 * w + ot) * 16 + c;
#pragma unroll
        for (int ks = 0; ks < 4; ++ks)
            bfO[ot][ks] = *(const s16x8*)&Wo16[o * 128 + ks * 32 + hi * 8];
    }

    // GEMM2: Out[r][o] = sum_j U^T[r,j] Wo[o,j]
    f32x4 acc2[8][2] = {};
#pragma unroll
    for (int rt8 = 0; rt8 < 8; ++rt8) {
        int rr = rt8 * 16 + c;
        s16x8 af[4];
#pragma unroll
        for (int ks = 0; ks < 4; ++ks)
            af[ks] = *(const s16x8*)&xsk[rr * 128 + ((ks * 32 + hi * 8) ^ ((rr & 7) << 3))];
#pragma unroll
        for (int ot = 0; ot < 2; ++ot)
#pragma unroll
            for (int ks = 0; ks < 4; ++ks)
                acc2[rt8][ot] = __builtin_amdgcn_mfma_f32_16x16x32_bf16(af[ks], bfO[ot][ks], acc2[rt8][ot], 0, 0, 0);
    }

#pragma unroll
    for (int rt8 = 0; rt8 < 8; ++rt8)
#pragma unroll
        for (int ot = 0; ot < 2; ++ot)
#pragma unroll
            for (int e = 0; e < 4; ++e) {
                int r = rt8 * 16 + hi * 4 + e;
                int o = (2 * w + ot) * 16 + c;
                float val = acc2[rt8][ot][e] + csl[r] * wsl[o] + bol[o];
                out[((long)r * ngrp + p) * 128 + o] = val;
            }
}

// ---------------- pass 2 (f32 fallback) if workspace too small — r3-style
__global__ __launch_bounds__(256) void k_out32(const float* __restrict__ x,
                                               const unsigned short* __restrict__ M16,
                                               const unsigned short* __restrict__ Wo16,
                                               const float* __restrict__ cvec,
                                               const float* __restrict__ wsum,
                                               const float* __restrict__ bo,
                                               float* __restrict__ out, int ngrp) {
    __shared__ short xsk[16384];
    __shared__ float csl[128], wsl[128], bol[128];
    int t = threadIdx.x;
    int l = t & 63, w = t >> 6, hi = l >> 4, c = l & 15;
    int p = blockIdx.x;

    s16x8 bfM[2][4];
#pragma unroll
    for (int rt = 0; rt < 2; ++rt) {
        int r = (2 * w + rt) * 16 + c;
#pragma unroll
        for (int ks = 0; ks < 4; ++ks)
            bfM[rt][ks] = *(const s16x8*)&M16[r * 128 + ks * 32 + hi * 8];
    }
    if (t < 128) { csl[t] = cvec[t]; wsl[t] = wsum[t]; bol[t] = bo[t]; }

    const fvec4* xg = (const fvec4*)x;
    long xbase = (long)p * 4096;
#pragma unroll 4
    for (int kk = 0; kk < 16; ++kk) {
        int ft = kk * 256 + t;
        fvec4 v = xg[xbase + ft];
        int j = ft >> 5, d0 = (ft & 31) * 4;
        uint64_t pk = 0;
#pragma unroll
        for (int e = 0; e < 4; ++e) pk |= (uint64_t)f2bf(v[e]) << (16 * e);
        *(uint64_t*)&xsk[j * 128 + (d0 ^ ((j & 7) << 3))] = pk;
    }
    __syncthreads();

    f32x4 acc[8][2] = {};
#pragma unroll
    for (int jt = 0; jt < 8; ++jt) {
        int j = jt * 16 + c;
        s16x8 af[4];
#pragma unroll
        for (int ks = 0; ks < 4; ++ks)
            af[ks] = *(const s16x8*)&xsk[j * 128 + ((ks * 32 + hi * 8) ^ ((j & 7) << 3))];
#pragma unroll
        for (int rt = 0; rt < 2; ++rt)
#pragma unroll
            for (int ks = 0; ks < 4; ++ks)
                acc[jt][rt] = __builtin_amdgcn_mfma_f32_16x16x32_bf16(af[ks], bfM[rt][ks], acc[jt][rt], 0, 0, 0);
    }
    __syncthreads();

#pragma unroll
    for (int jt = 0; jt < 8; ++jt)
#pragma unroll
        for (int rt = 0; rt < 2; ++rt) {
            int r = (2 * w + rt) * 16 + c;
            int j0 = jt * 16 + hi * 4;
            uint64_t pk = 0;
#pragma unroll
            for (int e = 0; e < 4; ++e) pk |= (uint64_t)f2bf(acc[jt][rt][e]) << (16 * e);
            *(uint64_t*)&xsk[r * 128 + (j0 ^ ((r & 7) << 3))] = pk;
        }
    __syncthreads();

    s16x8 bfO[2][4];
#pragma unroll
    for (int ot = 0; ot < 2; ++ot) {
        int o = (2 * w + ot) * 16 + c;
#pragma unroll
        for (int ks = 0; ks < 4; ++ks)
            bfO[ot][ks] = *(const s16x8*)&Wo16[o * 128 + ks * 32 + hi * 8];
    }

    f32x4 acc2[8][2] = {};
#pragma unroll
    for (int rt8 = 0; rt8 < 8; ++rt8) {
        int rr = rt8 * 16 + c;
        s16x8 af[4];
#pragma unroll
        for (int ks = 0; ks < 4; ++ks)
            af[ks] = *(const s16x8*)&xsk[rr * 128 + ((ks * 32 + hi * 8) ^ ((rr & 7) << 3))];
#pragma unroll
        for (int ot = 0; ot < 2; ++ot)
#pragma unroll
            for (int ks = 0; ks < 4; ++ks)
                acc2[rt8][ot] = __builtin_amdgcn_mfma_f32_16x16x32_bf16(af[ks], bfO[ot][ks], acc2[rt8][ot], 0, 0, 0);
    }

#pragma unroll
    for (int rt8 = 0; rt8 < 8; ++rt8)
#pragma unroll
        for (int ot = 0; ot < 2; ++ot)
#pragma unroll
            for (int e = 0; e < 4; ++e) {
                int r = rt8 * 16 + hi * 4 + e;
                int o = (2 * w + ot) * 16 + c;
                float val = acc2[rt8][ot][e] + csl[r] * wsl[o] + bol[o];
                out[((long)r * ngrp + p) * 128 + o] = val;
            }
}

// ------------------------------------------------------------------- launcher
extern "C" void kernel_launch(void* const* d_in, const int* in_sizes, int n_in,
                              void* d_out, int out_size, void* d_ws, size_t ws_size,
                              hipStream_t stream) {
    const float* x  = (const float*)d_in[0];
    const float* Wq = (const float*)d_in[1];
    const float* bq = (const float*)d_in[2];
    const float* Wk = (const float*)d_in[3];
    const float* bk = (const float*)d_in[4];
    const float* Wv = (const float*)d_in[5];
    const float* bv = (const float*)d_in[6];
    const float* Wo = (const float*)d_in[7];
    const float* bo = (const float*)d_in[8];
    float* out = (float*)d_out;
    float* ws = (float*)d_ws;

    int Bn  = in_sizes[0] / DD;      // 262144
    int nb1 = Bn / ROWS_PER_BLK;     // 256
    int ngrp = Bn / DD;              // 2048

    float* parts = ws;
    float* G     = ws + (size_t)nb1 * PART_STRIDE;
    float* svec  = G + 16384;
    float* cvec  = svec + 128;
    float* wsumv = cvec + 128;
    unsigned short* M16  = (unsigned short*)(wsumv + 128);
    unsigned short* Wo16 = M16 + 16384;
    unsigned short* x16  = Wo16 + 16384;
    size_t needed = (size_t)((char*)(x16 + (size_t)Bn * DD) - (char*)ws);
    bool use16 = ws_size >= needed;

    hipLaunchKernelGGL(k_gram, dim3(nb1), dim3(512), 0, stream,
                       x, ws, use16 ? x16 : (unsigned short*)nullptr);
    hipLaunchKernelGGL(k_reduce, dim3(513), dim3(256), 0, stream,
                       ws, G, svec, nb1);
    hipLaunchKernelGGL(k_mid, dim3(128), dim3(256), 0, stream,
                       G, svec, Wq, bq, Wk, bk, Wv, bv, Wo,
                       M16, Wo16, cvec, wsumv, (float)Bn);
    if (use16)
        hipLaunchKernelGGL(k_out16, dim3(ngrp), dim3(256), 0, stream,
                           x16, M16, Wo16, cvec, wsumv, bo, out, ngrp);
    else
        hipLaunchKernelGGL(k_out32, dim3(ngrp), dim3(256), 0, stream,
                           x, M16, Wo16, cvec, wsumv, bo, out, ngrp);
}